// Round 1
// baseline (179.282 us; speedup 1.0000x reference)
//
#include <hip/hip_runtime.h>
#include <hip/hip_fp16.h>

#define ALPHA 0.3f
#define B_SZ 4096
#define D_SZ 1024

typedef __attribute__((ext_vector_type(8))) _Float16 half8;
typedef __attribute__((ext_vector_type(4))) _Float16 half4;
typedef __attribute__((ext_vector_type(4))) float floatx4;

typedef __attribute__((address_space(1))) const void* gas_t;
typedef __attribute__((address_space(3))) void* las_t;

__device__ __forceinline__ float wave_reduce_add(float v) {
#pragma unroll
    for (int off = 32; off; off >>= 1) v += __shfl_xor(v, off);
    return v;
}

// ---------------------------------------------------------------------------
// prep: fp32 -> fp16 convert of both inputs, row norms x2/y2, and the exact
// per-anchor threshold m[i] = ||x_i - y_i|| + alpha (computed in fp32).
// One block per row (4096 blocks x 256 threads, 1 float4 per thread).
// ---------------------------------------------------------------------------
__global__ void __launch_bounds__(256) prep_kernel(
    const float* __restrict__ in1, const float* __restrict__ in2,
    _Float16* __restrict__ Xh, _Float16* __restrict__ Yh,
    float* __restrict__ x2, float* __restrict__ y2, float* __restrict__ mth) {
    int row = blockIdx.x;
    int t = threadIdx.x;
    const float4* a4 = (const float4*)(in1 + (size_t)row * D_SZ);
    const float4* b4 = (const float4*)(in2 + (size_t)row * D_SZ);
    float4 a = a4[t], b = b4[t];
    half4 ha = {(_Float16)a.x, (_Float16)a.y, (_Float16)a.z, (_Float16)a.w};
    half4 hb = {(_Float16)b.x, (_Float16)b.y, (_Float16)b.z, (_Float16)b.w};
    ((half4*)(Xh + (size_t)row * D_SZ))[t] = ha;
    ((half4*)(Yh + (size_t)row * D_SZ))[t] = hb;
    float sa = a.x * a.x + a.y * a.y + a.z * a.z + a.w * a.w;
    float sb = b.x * b.x + b.y * b.y + b.z * b.z + b.w * b.w;
    float d0 = a.x - b.x, d1 = a.y - b.y, d2v = a.z - b.z, d3 = a.w - b.w;
    float sd = d0 * d0 + d1 * d1 + d2v * d2v + d3 * d3;
    sa = wave_reduce_add(sa);
    sb = wave_reduce_add(sb);
    sd = wave_reduce_add(sd);
    __shared__ float red[3][4];
    int wave = t >> 6, lane = t & 63;
    if (lane == 0) { red[0][wave] = sa; red[1][wave] = sb; red[2][wave] = sd; }
    __syncthreads();
    if (t == 0) {
        x2[row] = red[0][0] + red[0][1] + red[0][2] + red[0][3];
        y2[row] = red[1][0] + red[1][1] + red[1][2] + red[1][3];
        mth[row] = sqrtf(red[2][0] + red[2][1] + red[2][2] + red[2][3]) + ALPHA;
    }
}

// ---------------------------------------------------------------------------
// GEMM: G = Xh @ Yh^T, 128x128 block tile, 4 waves (2x2) of 64x64,
// mfma_f32_16x16x32_f16, BK=32, global_load_lds width 16 (m97 structure).
// Epilogue: d2 = x2[i] + y2[j] - 2G, stored fp16 to both d2 and d2^T.
// ---------------------------------------------------------------------------
__global__ void __launch_bounds__(256) gemm_d2_kernel(
    const _Float16* __restrict__ Xh, const _Float16* __restrict__ Yh,
    const float* __restrict__ x2, const float* __restrict__ y2,
    _Float16* __restrict__ d2, _Float16* __restrict__ d2T) {
    __shared__ _Float16 As[128 * 32];   // rows x k, row-major, no pad (global_load_lds)
    __shared__ _Float16 Bs[128 * 32];
    int tid = threadIdx.x;
    int wave = tid >> 6, lane = tid & 63;
    int waveR = wave >> 1, waveC = wave & 1;
    int bx = blockIdx.x, by = blockIdx.y;
    int q = lane >> 4, mrow = lane & 15;

    floatx4 acc[4][4] = {};

    for (int k0 = 0; k0 < D_SZ; k0 += 32) {
        __syncthreads();  // previous iteration's LDS reads complete
#pragma unroll
        for (int s = 0; s < 2; ++s) {
            int c = s * 256 + tid;          // 16B chunk id, 512 chunks per tile
            int r = c >> 2, qq = c & 3;     // r = tile row, qq = 8-half slice
            const _Float16* ga = Xh + (size_t)(by * 128 + r) * D_SZ + k0 + qq * 8;
            const _Float16* gb = Yh + (size_t)(bx * 128 + r) * D_SZ + k0 + qq * 8;
            _Float16* la = &As[(s * 256 + wave * 64) * 8];  // wave-uniform base
            _Float16* lb = &Bs[(s * 256 + wave * 64) * 8];
            __builtin_amdgcn_global_load_lds((gas_t)(const void*)ga, (las_t)(void*)la, 16, 0, 0);
            __builtin_amdgcn_global_load_lds((gas_t)(const void*)gb, (las_t)(void*)lb, 16, 0, 0);
        }
        __syncthreads();  // staging complete (vmcnt drained before barrier)
        half8 af[4], bf[4];
#pragma unroll
        for (int mi = 0; mi < 4; ++mi)
            af[mi] = *(const half8*)&As[(waveR * 64 + mi * 16 + mrow) * 32 + q * 8];
#pragma unroll
        for (int ni = 0; ni < 4; ++ni)
            bf[ni] = *(const half8*)&Bs[(waveC * 64 + ni * 16 + mrow) * 32 + q * 8];
#pragma unroll
        for (int mi = 0; mi < 4; ++mi)
#pragma unroll
            for (int ni = 0; ni < 4; ++ni)
                acc[mi][ni] = __builtin_amdgcn_mfma_f32_16x16x32_f16(af[mi], bf[ni], acc[mi][ni], 0, 0, 0);
    }

    // Epilogue. C/D layout: col = lane&15, row = (lane>>4)*4 + reg.
#pragma unroll
    for (int ni = 0; ni < 4; ++ni) {
        int gc = bx * 128 + waveC * 64 + ni * 16 + mrow;
        float y2v = y2[gc];
#pragma unroll
        for (int mi = 0; mi < 4; ++mi) {
            int gr0 = by * 128 + waveR * 64 + mi * 16 + q * 4;
            floatx4 v = acc[mi][ni];
            _Float16 h0 = (_Float16)(x2[gr0 + 0] + y2v - 2.0f * v[0]);
            _Float16 h1 = (_Float16)(x2[gr0 + 1] + y2v - 2.0f * v[1]);
            _Float16 h2 = (_Float16)(x2[gr0 + 2] + y2v - 2.0f * v[2]);
            _Float16 h3 = (_Float16)(x2[gr0 + 3] + y2v - 2.0f * v[3]);
            d2[(size_t)(gr0 + 0) * B_SZ + gc] = h0;
            d2[(size_t)(gr0 + 1) * B_SZ + gc] = h1;
            d2[(size_t)(gr0 + 2) * B_SZ + gc] = h2;
            d2[(size_t)(gr0 + 3) * B_SZ + gc] = h3;
            half4 hv = {h0, h1, h2, h3};
            *(half4*)&d2T[(size_t)gc * B_SZ + gr0] = hv;  // 8B contiguous store
        }
    }
}

// ---------------------------------------------------------------------------
// select10: one wave per row. Each lane keeps its sorted 10-smallest (branchless
// min/max insertion over 64 values), then a 10-round wave-min merge produces the
// global 10 smallest distances. s = sum of clamped costs, z = count of zeros.
// Per-row partials; no global atomics.
// ---------------------------------------------------------------------------
__global__ void __launch_bounds__(256) select10_kernel(
    const _Float16* __restrict__ P, const float* __restrict__ mth,
    float* __restrict__ Srow, float* __restrict__ Zrow) {
    int wave = threadIdx.x >> 6, lane = threadIdx.x & 63;
    int r = blockIdx.x * 4 + wave;
    const half8* rowp = (const half8*)(P + (size_t)r * B_SZ);  // 512 half8/row
    float best[10];
#pragma unroll
    for (int i = 0; i < 10; ++i) best[i] = 3.0e38f;
#pragma unroll
    for (int it = 0; it < 8; ++it) {
        half8 v = rowp[it * 64 + lane];
        int colBase = (it * 64 + lane) * 8;
#pragma unroll
        for (int j = 0; j < 8; ++j) {
            float x = (float)v[j];
            if (colBase + j == r) x = 3.0e38f;  // exclude diagonal
#pragma unroll
            for (int p = 0; p < 10; ++p) {      // sorted insert (ascending)
                float lo = fminf(best[p], x);
                x = fmaxf(best[p], x);
                best[p] = lo;
            }
        }
    }
    float mrow = mth[r];
    float s = 0.f, z = 0.f;
#pragma unroll
    for (int round = 0; round < 10; ++round) {
        float v0 = best[0];
        float g = v0;
#pragma unroll
        for (int off = 32; off; off >>= 1) g = fminf(g, __shfl_xor(g, off));
        unsigned long long ball = __ballot(v0 == g);
        int leader = __ffsll(ball) - 1;
        if (lane == leader) {  // consume my front element
#pragma unroll
            for (int p = 0; p < 9; ++p) best[p] = best[p + 1];
            best[9] = 3.0e38f;
        }
        float d = sqrtf(fmaxf(g, 0.f));
        float c = fmaxf(mrow - d, 0.f);
        s += c;
        z += (c == 0.f) ? 1.f : 0.f;
    }
    if (lane == 0) { Srow[r] = s; Zrow[r] = z; }
}

// ---------------------------------------------------------------------------
// finalize: reduce per-row partials -> [loss_irr, loss_rii, bad_irr, bad_rii]
// ---------------------------------------------------------------------------
__global__ void __launch_bounds__(256) finalize_kernel(
    const float* __restrict__ Srow, const float* __restrict__ Zrow,
    float* __restrict__ out) {
    __shared__ float red[256][4];
    int t = threadIdx.x;
    float s0 = 0, s1 = 0, z0 = 0, z1 = 0;
    for (int k = t; k < B_SZ; k += 256) {
        s0 += Srow[k];
        s1 += Srow[B_SZ + k];
        z0 += Zrow[k];
        z1 += Zrow[B_SZ + k];
    }
    red[t][0] = s0; red[t][1] = s1; red[t][2] = z0; red[t][3] = z1;
    __syncthreads();
    for (int off = 128; off > 0; off >>= 1) {
        if (t < off) {
#pragma unroll
            for (int j = 0; j < 4; ++j) red[t][j] += red[t + off][j];
        }
        __syncthreads();
    }
    if (t == 0) {
        const float inv = 1.0f / (float)(B_SZ * 10);
        out[0] = red[0][0] * inv;  // loss_irr
        out[1] = red[0][1] * inv;  // loss_rii
        out[2] = red[0][2] * inv;  // bad_irr
        out[3] = red[0][3] * inv;  // bad_rii
    }
}

// ---------------------------------------------------------------------------
extern "C" void kernel_launch(void* const* d_in, const int* in_sizes, int n_in,
                              void* d_out, int out_size, void* d_ws, size_t ws_size,
                              hipStream_t stream) {
    const float* in1 = (const float*)d_in[0];
    const float* in2 = (const float*)d_in[1];
    float* out = (float*)d_out;

    char* ws = (char*)d_ws;
    const size_t MB = 1024 * 1024;
    _Float16* Xh  = (_Float16*)(ws);                 // 8 MiB
    _Float16* Yh  = (_Float16*)(ws + 8 * MB);        // 8 MiB
    _Float16* d2  = (_Float16*)(ws + 16 * MB);       // 32 MiB
    _Float16* d2T = (_Float16*)(ws + 48 * MB);       // 32 MiB
    float* x2   = (float*)(ws + 80 * MB);            // 16 KiB
    float* y2   = x2 + B_SZ;
    float* mth  = y2 + B_SZ;
    float* Srow = mth + B_SZ;                        // 2*B rows (irr then rii)
    float* Zrow = Srow + 2 * B_SZ;
    const size_t needed = 80 * MB + (size_t)(3 * B_SZ + 4 * B_SZ) * sizeof(float);
    if (ws_size < needed) return;  // fail loudly (absmax) rather than corrupt

    hipLaunchKernelGGL(prep_kernel, dim3(B_SZ), dim3(256), 0, stream,
                       in1, in2, Xh, Yh, x2, y2, mth);
    hipLaunchKernelGGL(gemm_d2_kernel, dim3(32, 32), dim3(256), 0, stream,
                       Xh, Yh, x2, y2, d2, d2T);
    hipLaunchKernelGGL(select10_kernel, dim3(1024), dim3(256), 0, stream,
                       d2, mth, Srow, Zrow);
    hipLaunchKernelGGL(select10_kernel, dim3(1024), dim3(256), 0, stream,
                       d2T, mth, Srow + B_SZ, Zrow + B_SZ);
    hipLaunchKernelGGL(finalize_kernel, dim3(1), dim3(256), 0, stream,
                       Srow, Zrow, out);
}

// Round 3
// 174.987 us; speedup vs baseline: 1.0245x; 1.0245x over previous
//
#include <hip/hip_runtime.h>
#include <hip/hip_fp16.h>

#define ALPHA 0.3f
#define B_SZ 4096
#define D_SZ 1024

typedef __attribute__((ext_vector_type(8))) _Float16 half8;
typedef __attribute__((ext_vector_type(4))) _Float16 half4;
typedef __attribute__((ext_vector_type(4))) float floatx4;

typedef __attribute__((address_space(1))) const void* gas_t;
typedef __attribute__((address_space(3))) void* las_t;

__device__ __forceinline__ float wave_reduce_add(float v) {
#pragma unroll
    for (int off = 32; off; off >>= 1) v += __shfl_xor(v, off);
    return v;
}

// ---------------------------------------------------------------------------
// prep: fp32 -> fp16 convert of both inputs, row norms x2/y2, and the exact
// per-anchor threshold m[i] = ||x_i - y_i|| + alpha (computed in fp32).
// ---------------------------------------------------------------------------
__global__ void __launch_bounds__(256) prep_kernel(
    const float* __restrict__ in1, const float* __restrict__ in2,
    _Float16* __restrict__ Xh, _Float16* __restrict__ Yh,
    float* __restrict__ x2, float* __restrict__ y2, float* __restrict__ mth) {
    int row = blockIdx.x;
    int t = threadIdx.x;
    const float4* a4 = (const float4*)(in1 + (size_t)row * D_SZ);
    const float4* b4 = (const float4*)(in2 + (size_t)row * D_SZ);
    float4 a = a4[t], b = b4[t];
    half4 ha = {(_Float16)a.x, (_Float16)a.y, (_Float16)a.z, (_Float16)a.w};
    half4 hb = {(_Float16)b.x, (_Float16)b.y, (_Float16)b.z, (_Float16)b.w};
    ((half4*)(Xh + (size_t)row * D_SZ))[t] = ha;
    ((half4*)(Yh + (size_t)row * D_SZ))[t] = hb;
    float sa = a.x * a.x + a.y * a.y + a.z * a.z + a.w * a.w;
    float sb = b.x * b.x + b.y * b.y + b.z * b.z + b.w * b.w;
    float d0 = a.x - b.x, d1 = a.y - b.y, d2v = a.z - b.z, d3 = a.w - b.w;
    float sd = d0 * d0 + d1 * d1 + d2v * d2v + d3 * d3;
    sa = wave_reduce_add(sa);
    sb = wave_reduce_add(sb);
    sd = wave_reduce_add(sd);
    __shared__ float red[3][4];
    int wave = t >> 6, lane = t & 63;
    if (lane == 0) { red[0][wave] = sa; red[1][wave] = sb; red[2][wave] = sd; }
    __syncthreads();
    if (t == 0) {
        x2[row] = red[0][0] + red[0][1] + red[0][2] + red[0][3];
        y2[row] = red[1][0] + red[1][1] + red[1][2] + red[1][3];
        mth[row] = sqrtf(red[2][0] + red[2][1] + red[2][2] + red[2][3]) + ALPHA;
    }
}

// ---------------------------------------------------------------------------
// GEMM: G = Xh @ Yh^T, 128x128 block tile, 4 waves (2x2) of 64x64,
// mfma_f32_16x16x32_f16, BK=32, global_load_lds width 16.
// LDS k-slice XOR swizzle: LDS chunk (r, j) holds global slice j ^ ((r>>1)&3);
// makes ds_read_b128 2-way-per-bank-group (free) instead of 8-way.
// Epilogue: d2 = x2[i] + y2[j] - 2G, stored fp16 to both d2 and d2^T.
// ---------------------------------------------------------------------------
__global__ void __launch_bounds__(256, 4) gemm_d2_kernel(
    const _Float16* __restrict__ Xh, const _Float16* __restrict__ Yh,
    const float* __restrict__ x2, const float* __restrict__ y2,
    _Float16* __restrict__ d2, _Float16* __restrict__ d2T) {
    __shared__ _Float16 As[128 * 32];
    __shared__ _Float16 Bs[128 * 32];
    int tid = threadIdx.x;
    int wave = tid >> 6, lane = tid & 63;
    int waveR = wave >> 1, waveC = wave & 1;
    int bx = blockIdx.x, by = blockIdx.y;
    int q = lane >> 4, mrow = lane & 15;

    floatx4 acc[4][4] = {};

    // Per-thread staging source (swizzled k-slice), invariant over k0.
    int c0 = tid, c1 = 256 + tid;
    int r0 = c0 >> 2, q0 = (c0 & 3) ^ ((r0 >> 1) & 3);
    int r1 = c1 >> 2, q1 = (c1 & 3) ^ ((r1 >> 1) & 3);
    const _Float16* gA0 = Xh + (size_t)(by * 128 + r0) * D_SZ + q0 * 8;
    const _Float16* gB0 = Yh + (size_t)(bx * 128 + r0) * D_SZ + q0 * 8;
    const _Float16* gA1 = Xh + (size_t)(by * 128 + r1) * D_SZ + q1 * 8;
    const _Float16* gB1 = Yh + (size_t)(bx * 128 + r1) * D_SZ + q1 * 8;
    _Float16* la0 = &As[(wave * 64) * 8];          // wave-uniform bases
    _Float16* lb0 = &Bs[(wave * 64) * 8];
    _Float16* la1 = &As[(256 + wave * 64) * 8];
    _Float16* lb1 = &Bs[(256 + wave * 64) * 8];

    // Reader LDS offsets (halves), swizzle-adjusted, invariant over k0.
    int aoff[4], boff[4];
#pragma unroll
    for (int mi = 0; mi < 4; ++mi) {
        int R = waveR * 64 + mi * 16 + mrow;
        aoff[mi] = R * 32 + (q ^ ((R >> 1) & 3)) * 8;
    }
#pragma unroll
    for (int ni = 0; ni < 4; ++ni) {
        int R = waveC * 64 + ni * 16 + mrow;
        boff[ni] = R * 32 + (q ^ ((R >> 1) & 3)) * 8;
    }

    for (int k0 = 0; k0 < D_SZ; k0 += 32) {
        __syncthreads();  // previous iteration's LDS reads complete
        __builtin_amdgcn_global_load_lds((gas_t)(const void*)(gA0 + k0), (las_t)(void*)la0, 16, 0, 0);
        __builtin_amdgcn_global_load_lds((gas_t)(const void*)(gB0 + k0), (las_t)(void*)lb0, 16, 0, 0);
        __builtin_amdgcn_global_load_lds((gas_t)(const void*)(gA1 + k0), (las_t)(void*)la1, 16, 0, 0);
        __builtin_amdgcn_global_load_lds((gas_t)(const void*)(gB1 + k0), (las_t)(void*)lb1, 16, 0, 0);
        __syncthreads();  // staging complete
        half8 af[4], bf[4];
#pragma unroll
        for (int mi = 0; mi < 4; ++mi) af[mi] = *(const half8*)&As[aoff[mi]];
#pragma unroll
        for (int ni = 0; ni < 4; ++ni) bf[ni] = *(const half8*)&Bs[boff[ni]];
#pragma unroll
        for (int mi = 0; mi < 4; ++mi)
#pragma unroll
            for (int ni = 0; ni < 4; ++ni)
                acc[mi][ni] = __builtin_amdgcn_mfma_f32_16x16x32_f16(af[mi], bf[ni], acc[mi][ni], 0, 0, 0);
    }

    // Epilogue. C/D layout: col = lane&15, row = (lane>>4)*4 + reg.
#pragma unroll
    for (int ni = 0; ni < 4; ++ni) {
        int gc = bx * 128 + waveC * 64 + ni * 16 + mrow;
        float y2v = y2[gc];
#pragma unroll
        for (int mi = 0; mi < 4; ++mi) {
            int gr0 = by * 128 + waveR * 64 + mi * 16 + q * 4;
            floatx4 v = acc[mi][ni];
            _Float16 h0 = (_Float16)(x2[gr0 + 0] + y2v - 2.0f * v[0]);
            _Float16 h1 = (_Float16)(x2[gr0 + 1] + y2v - 2.0f * v[1]);
            _Float16 h2 = (_Float16)(x2[gr0 + 2] + y2v - 2.0f * v[2]);
            _Float16 h3 = (_Float16)(x2[gr0 + 3] + y2v - 2.0f * v[3]);
            d2[(size_t)(gr0 + 0) * B_SZ + gc] = h0;
            d2[(size_t)(gr0 + 1) * B_SZ + gc] = h1;
            d2[(size_t)(gr0 + 2) * B_SZ + gc] = h2;
            d2[(size_t)(gr0 + 3) * B_SZ + gc] = h3;
            half4 hv = {h0, h1, h2, h3};
            *(half4*)&d2T[(size_t)gc * B_SZ + gr0] = hv;  // 8B contiguous store
        }
    }
}

// ---------------------------------------------------------------------------
// select10 (fused IRR+RII): one wave per logical row r in [0, 8192).
// r < 4096 -> row r of d2 (IRR); r >= 4096 -> row r-4096 of d2T (RII).
// ---------------------------------------------------------------------------
__global__ void __launch_bounds__(256) select10_kernel(
    const _Float16* __restrict__ d2, const float* __restrict__ mth,
    float* __restrict__ Srow, float* __restrict__ Zrow) {
    int wave = threadIdx.x >> 6, lane = threadIdx.x & 63;
    int r = blockIdx.x * 4 + wave;              // 0..8191
    int row = r & (B_SZ - 1);
    const _Float16* P = d2 + (size_t)(r >> 12) * ((size_t)16 * 1024 * 1024);
    const half8* rowp = (const half8*)(P + (size_t)row * B_SZ);
    float best[10];
#pragma unroll
    for (int i = 0; i < 10; ++i) best[i] = 3.0e38f;
#pragma unroll
    for (int it = 0; it < 8; ++it) {
        half8 v = rowp[it * 64 + lane];
        int colBase = (it * 64 + lane) * 8;
#pragma unroll
        for (int j = 0; j < 8; ++j) {
            float x = (float)v[j];
            if (colBase + j == row) x = 3.0e38f;  // exclude diagonal
#pragma unroll
            for (int p = 0; p < 10; ++p) {        // sorted insert (ascending)
                float lo = fminf(best[p], x);
                x = fmaxf(best[p], x);
                best[p] = lo;
            }
        }
    }
    float mrow = mth[row];
    float s = 0.f, z = 0.f;
#pragma unroll
    for (int round = 0; round < 10; ++round) {
        float v0 = best[0];
        float g = v0;
#pragma unroll
        for (int off = 32; off; off >>= 1) g = fminf(g, __shfl_xor(g, off));
        unsigned long long ball = __ballot(v0 == g);
        int leader = __ffsll(ball) - 1;
        if (lane == leader) {
#pragma unroll
            for (int p = 0; p < 9; ++p) best[p] = best[p + 1];
            best[9] = 3.0e38f;
        }
        float d = sqrtf(fmaxf(g, 0.f));
        float c = fmaxf(mrow - d, 0.f);
        s += c;
        z += (c == 0.f) ? 1.f : 0.f;
    }
    if (lane == 0) { Srow[r] = s; Zrow[r] = z; }
}

// ---------------------------------------------------------------------------
// finalize: reduce per-row partials -> [loss_irr, loss_rii, bad_irr, bad_rii]
// Srow/Zrow are 8192 floats each = 2048 float4: [0,1024) IRR, [1024,2048) RII.
// ---------------------------------------------------------------------------
__global__ void __launch_bounds__(256) finalize_kernel(
    const float* __restrict__ Srow, const float* __restrict__ Zrow,
    float* __restrict__ out) {
    __shared__ float red[256][4];
    int t = threadIdx.x;
    float s0 = 0, s1 = 0, z0 = 0, z1 = 0;
#pragma unroll
    for (int k = 0; k < 8; ++k) {
        int i = k * 256 + t;                     // 2048 float4 per array
        float4 sv = ((const float4*)Srow)[i];
        float4 zv = ((const float4*)Zrow)[i];
        float ss = sv.x + sv.y + sv.z + sv.w;
        float zz = zv.x + zv.y + zv.z + zv.w;
        if (i < 1024) { s0 += ss; z0 += zz; } else { s1 += ss; z1 += zz; }
    }
    red[t][0] = s0; red[t][1] = s1; red[t][2] = z0; red[t][3] = z1;
    __syncthreads();
    for (int off = 128; off > 0; off >>= 1) {
        if (t < off) {
#pragma unroll
            for (int j = 0; j < 4; ++j) red[t][j] += red[t + off][j];
        }
        __syncthreads();
    }
    if (t == 0) {
        const float inv = 1.0f / (float)(B_SZ * 10);
        out[0] = red[0][0] * inv;  // loss_irr
        out[1] = red[0][1] * inv;  // loss_rii
        out[2] = red[0][2] * inv;  // bad_irr
        out[3] = red[0][3] * inv;  // bad_rii
    }
}

// ---------------------------------------------------------------------------
extern "C" void kernel_launch(void* const* d_in, const int* in_sizes, int n_in,
                              void* d_out, int out_size, void* d_ws, size_t ws_size,
                              hipStream_t stream) {
    const float* in1 = (const float*)d_in[0];
    const float* in2 = (const float*)d_in[1];
    float* out = (float*)d_out;

    char* ws = (char*)d_ws;
    const size_t MB = 1024 * 1024;
    _Float16* Xh  = (_Float16*)(ws);                 // 8 MiB
    _Float16* Yh  = (_Float16*)(ws + 8 * MB);        // 8 MiB
    _Float16* d2  = (_Float16*)(ws + 16 * MB);       // 32 MiB
    _Float16* d2T = (_Float16*)(ws + 48 * MB);       // 32 MiB (d2 + 16M halves)
    float* x2   = (float*)(ws + 80 * MB);
    float* y2   = x2 + B_SZ;
    float* mth  = y2 + B_SZ;
    float* Srow = mth + B_SZ;                        // 2*B rows (irr then rii)
    float* Zrow = Srow + 2 * B_SZ;
    const size_t needed = 80 * MB + (size_t)(3 * B_SZ + 4 * B_SZ) * sizeof(float);
    if (ws_size < needed) return;
    (void)d2T;

    hipLaunchKernelGGL(prep_kernel, dim3(B_SZ), dim3(256), 0, stream,
                       in1, in2, Xh, Yh, x2, y2, mth);
    hipLaunchKernelGGL(gemm_d2_kernel, dim3(32, 32), dim3(256), 0, stream,
                       Xh, Yh, x2, y2, d2, d2T);
    hipLaunchKernelGGL(select10_kernel, dim3(2048), dim3(256), 0, stream,
                       d2, mth, Srow, Zrow);
    hipLaunchKernelGGL(finalize_kernel, dim3(1), dim3(256), 0, stream,
                       Srow, Zrow, out);
}

// Round 4
// 158.713 us; speedup vs baseline: 1.1296x; 1.1025x over previous
//
#include <hip/hip_runtime.h>
#include <hip/hip_fp16.h>

#define ALPHA 0.3f
#define B_SZ 4096
#define D_SZ 1024
#define CT_STRIDE 137   // 128 + 9: odd stride -> ~2-way LDS banks for row AND col reads
#define BIGF 3.0e38f

typedef __attribute__((ext_vector_type(8))) _Float16 half8;
typedef __attribute__((ext_vector_type(4))) _Float16 half4;
typedef __attribute__((ext_vector_type(4))) float floatx4;

typedef __attribute__((address_space(1))) const void* gas_t;
typedef __attribute__((address_space(3))) void* las_t;

__device__ __forceinline__ float wave_reduce_add(float v) {
#pragma unroll
    for (int off = 32; off; off >>= 1) v += __shfl_xor(v, off);
    return v;
}

// sorted ascending insert of x into best[0..9] (branchless)
__device__ __forceinline__ void insert10(float (&best)[10], float x) {
#pragma unroll
    for (int p = 0; p < 10; ++p) {
        float lo = fminf(best[p], x);
        x = fmaxf(best[p], x);
        best[p] = lo;
    }
}

// ---------------------------------------------------------------------------
// prep: fp32 -> fp16 convert of both inputs, row norms x2/y2, and the exact
// per-anchor threshold m[i] = ||x_i - y_i|| + alpha (computed in fp32).
// ---------------------------------------------------------------------------
__global__ void __launch_bounds__(256) prep_kernel(
    const float* __restrict__ in1, const float* __restrict__ in2,
    _Float16* __restrict__ Xh, _Float16* __restrict__ Yh,
    float* __restrict__ x2, float* __restrict__ y2, float* __restrict__ mth) {
    int row = blockIdx.x;
    int t = threadIdx.x;
    const float4* a4 = (const float4*)(in1 + (size_t)row * D_SZ);
    const float4* b4 = (const float4*)(in2 + (size_t)row * D_SZ);
    float4 a = a4[t], b = b4[t];
    half4 ha = {(_Float16)a.x, (_Float16)a.y, (_Float16)a.z, (_Float16)a.w};
    half4 hb = {(_Float16)b.x, (_Float16)b.y, (_Float16)b.z, (_Float16)b.w};
    ((half4*)(Xh + (size_t)row * D_SZ))[t] = ha;
    ((half4*)(Yh + (size_t)row * D_SZ))[t] = hb;
    float sa = a.x * a.x + a.y * a.y + a.z * a.z + a.w * a.w;
    float sb = b.x * b.x + b.y * b.y + b.z * b.z + b.w * b.w;
    float d0 = a.x - b.x, d1 = a.y - b.y, d2v = a.z - b.z, d3 = a.w - b.w;
    float sd = d0 * d0 + d1 * d1 + d2v * d2v + d3 * d3;
    sa = wave_reduce_add(sa);
    sb = wave_reduce_add(sb);
    sd = wave_reduce_add(sd);
    __shared__ float red[3][4];
    int wave = t >> 6, lane = t & 63;
    if (lane == 0) { red[0][wave] = sa; red[1][wave] = sb; red[2][wave] = sd; }
    __syncthreads();
    if (t == 0) {
        x2[row] = red[0][0] + red[0][1] + red[0][2] + red[0][3];
        y2[row] = red[1][0] + red[1][1] + red[1][2] + red[1][3];
        mth[row] = sqrtf(red[2][0] + red[2][1] + red[2][2] + red[2][3]) + ALPHA;
    }
}

// ---------------------------------------------------------------------------
// gemm_topk: G = Xh @ Yh^T tile (128x128), then FUSED selection epilogue:
// d2 tile -> LDS (fp16, stride 137), per-row top-10 over this tile's 128 cols
// (IRR) and per-col top-10 over 128 rows (RII), written as 2x10 candidates per
// (row, tile) half. d2 is never materialized in HBM (saves ~131 MB traffic).
// K-loop identical to round 3 (BK=32, XOR k-slice swizzle, global_load_lds 16B).
// ---------------------------------------------------------------------------
__global__ void __launch_bounds__(256, 4) gemm_topk_kernel(
    const _Float16* __restrict__ Xh, const _Float16* __restrict__ Yh,
    const float* __restrict__ x2, const float* __restrict__ y2,
    float* __restrict__ CandI, float* __restrict__ CandR) {
    __shared__ _Float16 smem[128 * CT_STRIDE];  // 35072 B; unions As+Bs (16 KB)
    _Float16* As = smem;             // 4096 halves
    _Float16* Bs = smem + 4096;      // 4096 halves
    int tid = threadIdx.x;
    int wave = tid >> 6, lane = tid & 63;
    int waveR = wave >> 1, waveC = wave & 1;
    int bx = blockIdx.x, by = blockIdx.y;
    int q = lane >> 4, mrow = lane & 15;

    floatx4 acc[4][4] = {};

    // Per-thread staging source (swizzled k-slice), invariant over k0.
    int c0 = tid, c1 = 256 + tid;
    int r0 = c0 >> 2, q0 = (c0 & 3) ^ ((r0 >> 1) & 3);
    int r1 = c1 >> 2, q1 = (c1 & 3) ^ ((r1 >> 1) & 3);
    const _Float16* gA0 = Xh + (size_t)(by * 128 + r0) * D_SZ + q0 * 8;
    const _Float16* gB0 = Yh + (size_t)(bx * 128 + r0) * D_SZ + q0 * 8;
    const _Float16* gA1 = Xh + (size_t)(by * 128 + r1) * D_SZ + q1 * 8;
    const _Float16* gB1 = Yh + (size_t)(bx * 128 + r1) * D_SZ + q1 * 8;
    _Float16* la0 = &As[(wave * 64) * 8];
    _Float16* lb0 = &Bs[(wave * 64) * 8];
    _Float16* la1 = &As[(256 + wave * 64) * 8];
    _Float16* lb1 = &Bs[(256 + wave * 64) * 8];

    int aoff[4], boff[4];
#pragma unroll
    for (int mi = 0; mi < 4; ++mi) {
        int R = waveR * 64 + mi * 16 + mrow;
        aoff[mi] = R * 32 + (q ^ ((R >> 1) & 3)) * 8;
    }
#pragma unroll
    for (int ni = 0; ni < 4; ++ni) {
        int R = waveC * 64 + ni * 16 + mrow;
        boff[ni] = R * 32 + (q ^ ((R >> 1) & 3)) * 8;
    }

    for (int k0 = 0; k0 < D_SZ; k0 += 32) {
        __syncthreads();
        __builtin_amdgcn_global_load_lds((gas_t)(const void*)(gA0 + k0), (las_t)(void*)la0, 16, 0, 0);
        __builtin_amdgcn_global_load_lds((gas_t)(const void*)(gB0 + k0), (las_t)(void*)lb0, 16, 0, 0);
        __builtin_amdgcn_global_load_lds((gas_t)(const void*)(gA1 + k0), (las_t)(void*)la1, 16, 0, 0);
        __builtin_amdgcn_global_load_lds((gas_t)(const void*)(gB1 + k0), (las_t)(void*)lb1, 16, 0, 0);
        __syncthreads();
        half8 af[4], bf[4];
#pragma unroll
        for (int mi = 0; mi < 4; ++mi) af[mi] = *(const half8*)&As[aoff[mi]];
#pragma unroll
        for (int ni = 0; ni < 4; ++ni) bf[ni] = *(const half8*)&Bs[boff[ni]];
#pragma unroll
        for (int mi = 0; mi < 4; ++mi)
#pragma unroll
            for (int ni = 0; ni < 4; ++ni)
                acc[mi][ni] = __builtin_amdgcn_mfma_f32_16x16x32_f16(af[mi], bf[ni], acc[mi][ni], 0, 0, 0);
    }
    __syncthreads();  // all waves done reading As/Bs before Ct overwrites them

    // Phase 1: d2 tile -> LDS fp16. C/D layout: col = lane&15, row = q*4 + reg.
    _Float16* Ct = smem;
#pragma unroll
    for (int ni = 0; ni < 4; ++ni) {
        int lc = waveC * 64 + ni * 16 + mrow;
        float y2v = y2[bx * 128 + lc];
#pragma unroll
        for (int mi = 0; mi < 4; ++mi) {
            int lr0 = waveR * 64 + mi * 16 + q * 4;
            int gr0 = by * 128 + lr0;
            floatx4 v = acc[mi][ni];
            Ct[(lr0 + 0) * CT_STRIDE + lc] = (_Float16)(x2[gr0 + 0] + y2v - 2.0f * v[0]);
            Ct[(lr0 + 1) * CT_STRIDE + lc] = (_Float16)(x2[gr0 + 1] + y2v - 2.0f * v[1]);
            Ct[(lr0 + 2) * CT_STRIDE + lc] = (_Float16)(x2[gr0 + 2] + y2v - 2.0f * v[2]);
            Ct[(lr0 + 3) * CT_STRIDE + lc] = (_Float16)(x2[gr0 + 3] + y2v - 2.0f * v[3]);
        }
    }
    __syncthreads();

    // Phase 2 (IRR): lane handles row (wave*32 + lane&31), half of the cols.
    {
        int rloc = wave * 32 + (lane & 31);
        int chalf = lane >> 5;
        int grow = by * 128 + rloc;
        int diagc = grow - bx * 128;  // only in [0,128) when bx==by
        float best[10];
#pragma unroll
        for (int i = 0; i < 10; ++i) best[i] = BIGF;
#pragma unroll 8
        for (int i = 0; i < 64; ++i) {
            int lc = chalf * 64 + i;
            float x = (float)Ct[rloc * CT_STRIDE + lc];
            if (lc == diagc) x = BIGF;
            insert10(best, x);
        }
        float* dst = CandI + ((size_t)grow * 32 + bx) * 20 + chalf * 10;
#pragma unroll
        for (int k = 0; k < 10; ++k) dst[k] = best[k];
    }

    // Phase 3 (RII): lane handles col (wave*32 + lane&31), half of the rows.
    {
        int cloc = wave * 32 + (lane & 31);
        int rhalf = lane >> 5;
        int gcol = bx * 128 + cloc;
        int diagr = gcol - by * 128;
        float best[10];
#pragma unroll
        for (int i = 0; i < 10; ++i) best[i] = BIGF;
#pragma unroll 8
        for (int i = 0; i < 64; ++i) {
            int lr = rhalf * 64 + i;
            float x = (float)Ct[lr * CT_STRIDE + cloc];
            if (lr == diagr) x = BIGF;
            insert10(best, x);
        }
        float* dst = CandR + ((size_t)gcol * 32 + by) * 20 + rhalf * 10;
#pragma unroll
        for (int k = 0; k < 10; ++k) dst[k] = best[k];
    }
}

// ---------------------------------------------------------------------------
// merge: one wave per logical row r in [0, 8192). Reads 640 candidates
// (32 tiles x 2 halves x 10), selects global 10 smallest, computes
// s = sum(max(m - sqrt(d2), 0)) and z = count of zeros over the 10.
// ---------------------------------------------------------------------------
__global__ void __launch_bounds__(256) merge_kernel(
    const float* __restrict__ CandI, const float* __restrict__ CandR,
    const float* __restrict__ mth,
    float* __restrict__ Srow, float* __restrict__ Zrow) {
    int wave = threadIdx.x >> 6, lane = threadIdx.x & 63;
    int r = blockIdx.x * 4 + wave;              // 0..8191
    int row = r & (B_SZ - 1);
    const float* cp = ((r < B_SZ) ? CandI : CandR) + (size_t)row * 640;
    float best[10];
#pragma unroll
    for (int i = 0; i < 10; ++i) best[i] = BIGF;
#pragma unroll
    for (int j = 0; j < 10; ++j) insert10(best, cp[j * 64 + lane]);

    float mrow = mth[row];
    float s = 0.f, z = 0.f;
#pragma unroll
    for (int round = 0; round < 10; ++round) {
        float v0 = best[0];
        float g = v0;
#pragma unroll
        for (int off = 32; off; off >>= 1) g = fminf(g, __shfl_xor(g, off));
        unsigned long long ball = __ballot(v0 == g);
        int leader = __ffsll(ball) - 1;
        if (lane == leader) {
#pragma unroll
            for (int p = 0; p < 9; ++p) best[p] = best[p + 1];
            best[9] = BIGF;
        }
        float d = sqrtf(fmaxf(g, 0.f));
        float c = fmaxf(mrow - d, 0.f);
        s += c;
        z += (c == 0.f) ? 1.f : 0.f;
    }
    if (lane == 0) { Srow[r] = s; Zrow[r] = z; }
}

// ---------------------------------------------------------------------------
// finalize: reduce per-row partials -> [loss_irr, loss_rii, bad_irr, bad_rii]
// Srow/Zrow are 8192 floats each = 2048 float4: [0,1024) IRR, [1024,2048) RII.
// ---------------------------------------------------------------------------
__global__ void __launch_bounds__(256) finalize_kernel(
    const float* __restrict__ Srow, const float* __restrict__ Zrow,
    float* __restrict__ out) {
    __shared__ float red[256][4];
    int t = threadIdx.x;
    float s0 = 0, s1 = 0, z0 = 0, z1 = 0;
#pragma unroll
    for (int k = 0; k < 8; ++k) {
        int i = k * 256 + t;
        float4 sv = ((const float4*)Srow)[i];
        float4 zv = ((const float4*)Zrow)[i];
        float ss = sv.x + sv.y + sv.z + sv.w;
        float zz = zv.x + zv.y + zv.z + zv.w;
        if (i < 1024) { s0 += ss; z0 += zz; } else { s1 += ss; z1 += zz; }
    }
    red[t][0] = s0; red[t][1] = s1; red[t][2] = z0; red[t][3] = z1;
    __syncthreads();
    for (int off = 128; off > 0; off >>= 1) {
        if (t < off) {
#pragma unroll
            for (int j = 0; j < 4; ++j) red[t][j] += red[t + off][j];
        }
        __syncthreads();
    }
    if (t == 0) {
        const float inv = 1.0f / (float)(B_SZ * 10);
        out[0] = red[0][0] * inv;  // loss_irr
        out[1] = red[0][1] * inv;  // loss_rii
        out[2] = red[0][2] * inv;  // bad_irr
        out[3] = red[0][3] * inv;  // bad_rii
    }
}

// ---------------------------------------------------------------------------
extern "C" void kernel_launch(void* const* d_in, const int* in_sizes, int n_in,
                              void* d_out, int out_size, void* d_ws, size_t ws_size,
                              hipStream_t stream) {
    const float* in1 = (const float*)d_in[0];
    const float* in2 = (const float*)d_in[1];
    float* out = (float*)d_out;

    char* ws = (char*)d_ws;
    const size_t MB = 1024 * 1024;
    _Float16* Xh = (_Float16*)(ws);                  // 8 MiB
    _Float16* Yh = (_Float16*)(ws + 8 * MB);         // 8 MiB
    float* CandI = (float*)(ws + 16 * MB);           // 4096*32*20*4 = 10.49 MB
    float* CandR = (float*)(ws + 27 * MB);           // 10.49 MB
    float* x2   = (float*)(ws + 38 * MB);
    float* y2   = x2 + B_SZ;
    float* mth  = y2 + B_SZ;
    float* Srow = mth + B_SZ;                        // 2*B rows (irr then rii)
    float* Zrow = Srow + 2 * B_SZ;
    const size_t needed = 38 * MB + (size_t)(3 * B_SZ + 4 * B_SZ) * sizeof(float);
    if (ws_size < needed) return;

    hipLaunchKernelGGL(prep_kernel, dim3(B_SZ), dim3(256), 0, stream,
                       in1, in2, Xh, Yh, x2, y2, mth);
    hipLaunchKernelGGL(gemm_topk_kernel, dim3(32, 32), dim3(256), 0, stream,
                       Xh, Yh, x2, y2, CandI, CandR);
    hipLaunchKernelGGL(merge_kernel, dim3(2048), dim3(256), 0, stream,
                       CandI, CandR, mth, Srow, Zrow);
    hipLaunchKernelGGL(finalize_kernel, dim3(1), dim3(256), 0, stream,
                       Srow, Zrow, out);
}